// Round 5
// baseline (2554.732 us; speedup 1.0000x reference)
//
#include <hip/hip_runtime.h>
#include <cmath>

#define B_ 4
#define C_ 256
#define P_ 4096   // H*W
#define N_ 4096   // tokens per batch (raw-reshape token count)

// ---------------------------------------------------------------------------
// Projection: Y[b][o][p] = sum_c W[o][c] * X[b][c][p] + bias[o]
// Raw-reshape note: Y stored (o,p) row-major IS the (n,c) token matrix
// row-major (n*256+c == o*4096+p), so attention reads it linearly.
// grid (P_/64, C_/64, B_*3), block 256 (16x16), 4x4 micro-tile.
// ---------------------------------------------------------------------------
__global__ __launch_bounds__(256) void proj_kernel(
    const float* __restrict__ tgt, const float* __restrict__ src,
    const float* __restrict__ qw, const float* __restrict__ qb,
    const float* __restrict__ kw, const float* __restrict__ kb,
    const float* __restrict__ vw, const float* __restrict__ vb,
    float* __restrict__ Qo, float* __restrict__ Ko, float* __restrict__ Vo)
{
    const int p0 = blockIdx.x * 64;
    const int o0 = blockIdx.y * 64;
    const int bz = blockIdx.z;
    const int b  = bz / 3, pr = bz % 3;

    const float* X  = (pr == 0 ? tgt : src) + (size_t)b * C_ * P_;
    const float* Wm = (pr == 0 ? qw : (pr == 1 ? kw : vw));
    const float* bi = (pr == 0 ? qb : (pr == 1 ? kb : vb));
    float*       Y  = (pr == 0 ? Qo : (pr == 1 ? Ko : Vo)) + (size_t)b * C_ * P_;

    __shared__ float WsT[32][68];  // [k][o], padded (float4-aligned stride)
    __shared__ float Xs[32][64];   // [k][p]

    const int tid = threadIdx.x;
    const int tx = tid & 15, ty = tid >> 4;

    float acc[4][4] = {};

    for (int kk = 0; kk < C_; kk += 32) {
        __syncthreads();
        // W chunk 64x32, coalesced global, transposed into LDS
        #pragma unroll
        for (int i = 0; i < 8; ++i) {
            int flat = tid + i * 256;          // 0..2047
            int r = flat >> 5, c = flat & 31;
            WsT[c][r] = Wm[(o0 + r) * C_ + (kk + c)];
        }
        // X chunk 32x64, coalesced
        #pragma unroll
        for (int i = 0; i < 8; ++i) {
            int flat = tid + i * 256;
            int r = flat >> 6, c = flat & 63;
            Xs[r][c] = X[(size_t)(kk + r) * P_ + (p0 + c)];
        }
        __syncthreads();
        #pragma unroll
        for (int k = 0; k < 32; ++k) {
            float4 a4 = *(const float4*)&WsT[k][ty * 4];
            float4 x4 = *(const float4*)&Xs[k][tx * 4];
            const float av[4] = {a4.x, a4.y, a4.z, a4.w};
            const float xv[4] = {x4.x, x4.y, x4.z, x4.w};
            #pragma unroll
            for (int i = 0; i < 4; ++i)
                #pragma unroll
                for (int j = 0; j < 4; ++j)
                    acc[i][j] += av[i] * xv[j];
        }
    }

    #pragma unroll
    for (int i = 0; i < 4; ++i) {
        float bv = bi[o0 + ty * 4 + i];
        float4 o;
        o.x = acc[i][0] + bv; o.y = acc[i][1] + bv;
        o.z = acc[i][2] + bv; o.w = acc[i][3] + bv;
        *(float4*)&Y[(size_t)(o0 + ty * 4 + i) * P_ + p0 + tx * 4] = o;
    }
}

// ---------------------------------------------------------------------------
// Flash attention, fp32. One block per (batch, 64-query-row tile).
// Token matrices are the proj buffers viewed (N_, C_) row-major.
// Thread layout: tx=tid&15, ty=tid>>4.
//   S tile 64x64: thread owns rows ty*4+i, cols j*16+tx  (4x4)
//   O tile 64x256: thread owns rows ty*4+i, cols cc*64 + tx*4 + j (4x16)
// LDS: Qs 65KB + Ks 17KB + Ps 17KB + Vs 17KB = 116KB -> 1 block/CU.
// Grid = 64 x 4 = 256 blocks = exactly one per CU.
// ---------------------------------------------------------------------------
__global__ __launch_bounds__(256) void attn_kernel(
    const float* __restrict__ Q, const float* __restrict__ K,
    const float* __restrict__ V, float* __restrict__ O)
{
    const int b  = blockIdx.y;
    const int n0 = blockIdx.x * 64;
    const size_t base = (size_t)b * N_ * C_;

    __shared__ float Qs[64][260];  // full 256-col Q tile, padded
    __shared__ float Ks[64][68];   // 64-row x 64-k chunk
    __shared__ float Ps[64][68];   // P tile
    __shared__ float Vs[64][68];   // 64-row x 64-col chunk

    const int tid = threadIdx.x;
    const int tx = tid & 15, ty = tid >> 4;

    // ---- load Q tile (float4, coalesced) ----
    #pragma unroll
    for (int i = 0; i < 16; ++i) {
        int flat = tid + i * 256;            // 0..4095 float4s
        int r = flat >> 6, c = (flat & 63) * 4;
        *(float4*)&Qs[r][c] = *(const float4*)&Q[base + (size_t)(n0 + r) * C_ + c];
    }

    float m_run[4], l_run[4];
    float o_acc[4][16] = {};
    #pragma unroll
    for (int i = 0; i < 4; ++i) { m_run[i] = -1e30f; l_run[i] = 0.0f; }

    for (int m0 = 0; m0 < N_; m0 += 64) {
        // ---------------- S = Q K^T for this 64-m tile ----------------
        float s[4][4] = {};
        for (int kk = 0; kk < C_; kk += 64) {
            __syncthreads();   // prior consumers of Ks (and first-iter Qs) done
            #pragma unroll
            for (int i = 0; i < 4; ++i) {
                int flat = tid + i * 256;        // 0..1023 float4s
                int r = flat >> 4, c = (flat & 15) * 4;
                *(float4*)&Ks[r][c] =
                    *(const float4*)&K[base + (size_t)(m0 + r) * C_ + kk + c];
            }
            __syncthreads();
            #pragma unroll
            for (int k = 0; k < 64; k += 4) {
                float4 q4[4], k4[4];
                #pragma unroll
                for (int i = 0; i < 4; ++i)
                    q4[i] = *(const float4*)&Qs[ty * 4 + i][kk + k];
                #pragma unroll
                for (int j = 0; j < 4; ++j)
                    k4[j] = *(const float4*)&Ks[j * 16 + tx][k];
                #pragma unroll
                for (int i = 0; i < 4; ++i) {
                    #pragma unroll
                    for (int j = 0; j < 4; ++j) {
                        s[i][j] += q4[i].x * k4[j].x;
                        s[i][j] += q4[i].y * k4[j].y;
                        s[i][j] += q4[i].z * k4[j].z;
                        s[i][j] += q4[i].w * k4[j].w;
                    }
                }
            }
        }

        // ---------------- online softmax (rows ty*4+i, 16-lane groups) ----
        #pragma unroll
        for (int i = 0; i < 4; ++i) {
            float mt = fmaxf(fmaxf(s[i][0], s[i][1]), fmaxf(s[i][2], s[i][3]));
            #pragma unroll
            for (int d = 1; d < 16; d <<= 1)
                mt = fmaxf(mt, __shfl_xor(mt, d, 64));
            float mnew  = fmaxf(m_run[i], mt);
            float scale = __expf(m_run[i] - mnew);
            float p0v = __expf(s[i][0] - mnew);
            float p1v = __expf(s[i][1] - mnew);
            float p2v = __expf(s[i][2] - mnew);
            float p3v = __expf(s[i][3] - mnew);
            float ssum = p0v + p1v + p2v + p3v;
            #pragma unroll
            for (int d = 1; d < 16; d <<= 1)
                ssum += __shfl_xor(ssum, d, 64);
            l_run[i] = l_run[i] * scale + ssum;
            m_run[i] = mnew;
            #pragma unroll
            for (int jj = 0; jj < 16; ++jj) o_acc[i][jj] *= scale;
            Ps[ty * 4 + i][0 * 16 + tx] = p0v;
            Ps[ty * 4 + i][1 * 16 + tx] = p1v;
            Ps[ty * 4 + i][2 * 16 + tx] = p2v;
            Ps[ty * 4 + i][3 * 16 + tx] = p3v;
        }

        // ---------------- O += P V, 64-col chunks ----------------
        for (int cc = 0; cc < 4; ++cc) {
            __syncthreads();  // Ps fully written (cc=0) / prior Vs consumed
            #pragma unroll
            for (int i = 0; i < 4; ++i) {
                int flat = tid + i * 256;
                int r = flat >> 4, c = (flat & 15) * 4;
                *(float4*)&Vs[r][c] =
                    *(const float4*)&V[base + (size_t)(m0 + r) * C_ + cc * 64 + c];
            }
            __syncthreads();
            #pragma unroll
            for (int m4 = 0; m4 < 16; ++m4) {
                float4 p4[4];
                #pragma unroll
                for (int i = 0; i < 4; ++i)
                    p4[i] = *(const float4*)&Ps[ty * 4 + i][m4 * 4];
                #pragma unroll
                for (int mm = 0; mm < 4; ++mm) {
                    float4 v4 = *(const float4*)&Vs[m4 * 4 + mm][tx * 4];
                    const float vv[4] = {v4.x, v4.y, v4.z, v4.w};
                    const float pp[4] = {
                        ((const float*)&p4[0])[mm], ((const float*)&p4[1])[mm],
                        ((const float*)&p4[2])[mm], ((const float*)&p4[3])[mm]};
                    #pragma unroll
                    for (int i = 0; i < 4; ++i)
                        #pragma unroll
                        for (int j = 0; j < 4; ++j)
                            o_acc[i][cc * 4 + j] += pp[i] * vv[j];
                }
            }
        }
    }

    // ---------------- epilogue: normalize + store (raw-reshape = linear) ----
    #pragma unroll
    for (int i = 0; i < 4; ++i) {
        float inv = 1.0f / l_run[i];
        #pragma unroll
        for (int cc = 0; cc < 4; ++cc) {
            float4 o;
            o.x = o_acc[i][cc * 4 + 0] * inv;
            o.y = o_acc[i][cc * 4 + 1] * inv;
            o.z = o_acc[i][cc * 4 + 2] * inv;
            o.w = o_acc[i][cc * 4 + 3] * inv;
            *(float4*)&O[base + (size_t)(n0 + ty * 4 + i) * C_ + cc * 64 + tx * 4] = o;
        }
    }
}

// ---------------------------------------------------------------------------
extern "C" void kernel_launch(void* const* d_in, const int* in_sizes, int n_in,
                              void* d_out, int out_size, void* d_ws, size_t ws_size,
                              hipStream_t stream)
{
    const float* tgt = (const float*)d_in[0];
    const float* src = (const float*)d_in[1];
    const float* qw  = (const float*)d_in[2];
    const float* qb  = (const float*)d_in[3];
    const float* kw  = (const float*)d_in[4];
    const float* kb  = (const float*)d_in[5];
    const float* vw  = (const float*)d_in[6];
    const float* vb  = (const float*)d_in[7];
    float* out = (float*)d_out;

    // ws: Q | K | V token matrices, 16.8 MB each (50.3 MB total)
    float* Qb = (float*)d_ws;
    float* Kb = Qb + (size_t)B_ * N_ * C_;
    float* Vb = Kb + (size_t)B_ * N_ * C_;

    dim3 pgrid(P_ / 64, C_ / 64, B_ * 3);
    proj_kernel<<<pgrid, 256, 0, stream>>>(tgt, src, qw, qb, kw, kb, vw, vb,
                                           Qb, Kb, Vb);

    dim3 agrid(N_ / 64, B_);
    attn_kernel<<<agrid, 256, 0, stream>>>(Qb, Kb, Vb, out);
}

// Round 6
// 1278.326 us; speedup vs baseline: 1.9985x; 1.9985x over previous
//
#include <hip/hip_runtime.h>
#include <cmath>

#define B_ 4
#define C_ 256
#define P_ 4096   // H*W
#define N_ 4096   // tokens per batch (raw-reshape token count)

typedef __bf16 bf16x8 __attribute__((ext_vector_type(8)));
typedef __bf16 bf16x4 __attribute__((ext_vector_type(4)));
typedef float  f32x4  __attribute__((ext_vector_type(4)));

// ---------------------------------------------------------------------------
// Projection GEMM (fp32 compute, validated structure) with bf16 hi/lo split
// output. Y viewed linearly IS the (n,c) token matrix (raw-reshape identity).
// grid (P_/64, C_/64, B_), block 256.
// ---------------------------------------------------------------------------
__global__ __launch_bounds__(256) void proj_kernel(
    const float* __restrict__ X, const float* __restrict__ W,
    const float* __restrict__ bias,
    __bf16* __restrict__ Yh, __bf16* __restrict__ Yl)
{
    const int p0 = blockIdx.x * 64;
    const int o0 = blockIdx.y * 64;
    const int b  = blockIdx.z;

    const float* Xb = X + (size_t)b * C_ * P_;
    const size_t ybase = (size_t)b * C_ * P_;

    __shared__ float WsT[32][68];
    __shared__ float Xs[32][64];

    const int tid = threadIdx.x;
    const int tx = tid & 15, ty = tid >> 4;

    float acc[4][4] = {};

    for (int kk = 0; kk < C_; kk += 32) {
        __syncthreads();
        #pragma unroll
        for (int i = 0; i < 8; ++i) {
            int flat = tid + i * 256;
            int r = flat >> 5, c = flat & 31;
            WsT[c][r] = W[(o0 + r) * C_ + (kk + c)];
        }
        #pragma unroll
        for (int i = 0; i < 8; ++i) {
            int flat = tid + i * 256;
            int r = flat >> 6, c = flat & 63;
            Xs[r][c] = Xb[(size_t)(kk + r) * P_ + (p0 + c)];
        }
        __syncthreads();
        #pragma unroll
        for (int k = 0; k < 32; ++k) {
            float4 a4 = *(const float4*)&WsT[k][ty * 4];
            float4 x4 = *(const float4*)&Xs[k][tx * 4];
            const float av[4] = {a4.x, a4.y, a4.z, a4.w};
            const float xv[4] = {x4.x, x4.y, x4.z, x4.w};
            #pragma unroll
            for (int i = 0; i < 4; ++i)
                #pragma unroll
                for (int j = 0; j < 4; ++j)
                    acc[i][j] += av[i] * xv[j];
        }
    }

    #pragma unroll
    for (int i = 0; i < 4; ++i) {
        float bv = bias[o0 + ty * 4 + i];
        bf16x4 h, l;
        #pragma unroll
        for (int j = 0; j < 4; ++j) {
            float y  = acc[i][j] + bv;
            __bf16 hh = (__bf16)y;                    // RNE
            __bf16 ll = (__bf16)(y - (float)hh);
            h[j] = hh; l[j] = ll;
        }
        size_t off = ybase + (size_t)(o0 + ty * 4 + i) * P_ + p0 + tx * 4;
        *(bf16x4*)&Yh[off] = h;
        *(bf16x4*)&Yl[off] = l;
    }
}

// ---------------------------------------------------------------------------
// Transpose V (n,c) -> Vt (c,n), bf16 bits only. grid (64, 4, 8):
// z = batch*2 + buf. Tile 64(n) x 64(c) through LDS.
// ---------------------------------------------------------------------------
__global__ __launch_bounds__(256) void transpose_kernel(
    const ushort* __restrict__ SrcH, const ushort* __restrict__ SrcL,
    ushort* __restrict__ DstH, ushort* __restrict__ DstL)
{
    const int n0 = blockIdx.x * 64;
    const int c0 = blockIdx.y * 64;
    const int b  = blockIdx.z >> 1;
    const int bf = blockIdx.z & 1;

    const ushort* src = (bf ? SrcL : SrcH) + (size_t)b * N_ * C_;
    ushort*       dst = (bf ? DstL : DstH) + (size_t)b * N_ * C_;

    __shared__ ushort T[64][65];
    const int tid = threadIdx.x;

    #pragma unroll
    for (int it = 0; it < 4; ++it) {
        int e = tid + it * 256;          // 0..1023
        int r = e >> 4, c4 = (e & 15) * 4;
        *(ushort4*)&T[r][c4] = *(const ushort4*)&src[(size_t)(n0 + r) * C_ + c0 + c4];
    }
    __syncthreads();
    #pragma unroll
    for (int it = 0; it < 4; ++it) {
        int e = tid + it * 256;
        int cr = e >> 4, nl = (e & 15) * 4;
        ushort4 v;
        v.x = T[nl + 0][cr]; v.y = T[nl + 1][cr];
        v.z = T[nl + 2][cr]; v.w = T[nl + 3][cr];
        *(ushort4*)&dst[(size_t)(c0 + cr) * N_ + n0 + nl] = v;
    }
}

// ---------------------------------------------------------------------------
// Split-bf16 MFMA flash attention. Block = 256 thr (4 waves), grid (64, B).
// Wave w owns 16 q-rows (n0 + w*16 + ..). Per m-tile of 64 tokens:
//   QK^T: A=Q frags (reg), B=K^T frags (direct global, 16B/lane), 96 mfma
//   softmax: shfl over 16-lane groups (D layout: row i=(lg)*4+r, col j=l15)
//   PV:   A=P frags (per-wave LDS, 72-padded), B=Vt frags (global), 96 mfma
// No block barrier on K/V path; one __syncthreads per tile for P_lds safety.
// ---------------------------------------------------------------------------
__global__ __launch_bounds__(256) void attn_kernel(
    const __bf16* __restrict__ Qh, const __bf16* __restrict__ Ql,
    const __bf16* __restrict__ Kh, const __bf16* __restrict__ Kl,
    const __bf16* __restrict__ Vth, const __bf16* __restrict__ Vtl,
    float* __restrict__ O)
{
    const int b  = blockIdx.y;
    const int n0 = blockIdx.x * 64;
    const size_t base = (size_t)b * N_ * C_;   // elem count, same for Vt

    const int tid  = threadIdx.x;
    const int w    = tid >> 6;
    const int lane = tid & 63;
    const int l15  = lane & 15;
    const int lg   = lane >> 4;

    __shared__ __align__(16) __bf16 Pl[4][2][16][72];

    // ---- Q fragments: row i = l15, k-cols = kk*32 + lg*8 (+0..7) ----
    const __bf16* qh_p = Qh + base + (size_t)(n0 + w * 16 + l15) * C_ + lg * 8;
    const __bf16* ql_p = Ql + base + (size_t)(n0 + w * 16 + l15) * C_ + lg * 8;
    bf16x8 qfh[8], qfl[8];
    #pragma unroll
    for (int k = 0; k < 8; ++k) {
        qfh[k] = *(const bf16x8*)(qh_p + k * 32);
        qfl[k] = *(const bf16x8*)(ql_p + k * 32);
    }

    f32x4 oc[16];
    #pragma unroll
    for (int c = 0; c < 16; ++c) oc[c] = (f32x4){0.f, 0.f, 0.f, 0.f};
    float m_run[4] = {-1e30f, -1e30f, -1e30f, -1e30f};
    float l_run[4] = {0.f, 0.f, 0.f, 0.f};

    for (int mt = 0; mt < N_; mt += 64) {
        // ---------------- S = Q K^T ----------------
        f32x4 s[4];
        #pragma unroll
        for (int js = 0; js < 4; ++js) s[js] = (f32x4){0.f, 0.f, 0.f, 0.f};

        const __bf16* kh_p = Kh + base + (size_t)(mt + l15) * C_ + lg * 8;
        const __bf16* kl_p = Kl + base + (size_t)(mt + l15) * C_ + lg * 8;

        #pragma unroll
        for (int kk = 0; kk < 8; ++kk) {
            #pragma unroll
            for (int js = 0; js < 4; ++js) {
                bf16x8 kfh = *(const bf16x8*)(kh_p + js * 16 * C_ + kk * 32);
                bf16x8 kfl = *(const bf16x8*)(kl_p + js * 16 * C_ + kk * 32);
                s[js] = __builtin_amdgcn_mfma_f32_16x16x32_bf16(qfh[kk], kfh, s[js], 0, 0, 0);
                s[js] = __builtin_amdgcn_mfma_f32_16x16x32_bf16(qfh[kk], kfl, s[js], 0, 0, 0);
                s[js] = __builtin_amdgcn_mfma_f32_16x16x32_bf16(qfl[kk], kfh, s[js], 0, 0, 0);
            }
        }

        // ---------------- online softmax ----------------
        // lane holds S[i = lg*4+r][token = mt + js*16 + l15]
        float scale_[4];
        #pragma unroll
        for (int r = 0; r < 4; ++r) {
            float mx = fmaxf(fmaxf(s[0][r], s[1][r]), fmaxf(s[2][r], s[3][r]));
            #pragma unroll
            for (int d = 1; d < 16; d <<= 1)
                mx = fmaxf(mx, __shfl_xor(mx, d, 64));
            float mnew = fmaxf(m_run[r], mx);
            scale_[r] = __expf(m_run[r] - mnew);
            float ss = 0.f;
            #pragma unroll
            for (int js = 0; js < 4; ++js) {
                float pv = __expf(s[js][r] - mnew);
                s[js][r] = pv;
                ss += pv;
            }
            #pragma unroll
            for (int d = 1; d < 16; d <<= 1)
                ss += __shfl_xor(ss, d, 64);
            l_run[r] = l_run[r] * scale_[r] + ss;
            m_run[r] = mnew;
        }

        // ---- P -> LDS (hi/lo), row i, col m-local ----
        #pragma unroll
        for (int js = 0; js < 4; ++js)
            #pragma unroll
            for (int r = 0; r < 4; ++r) {
                float pv = s[js][r];
                __bf16 hh = (__bf16)pv;
                __bf16 ll = (__bf16)(pv - (float)hh);
                Pl[w][0][lg * 4 + r][js * 16 + l15] = hh;
                Pl[w][1][lg * 4 + r][js * 16 + l15] = ll;
            }

        // rescale O accumulators (independent of P_lds)
        #pragma unroll
        for (int c = 0; c < 16; ++c)
            #pragma unroll
            for (int r = 0; r < 4; ++r)
                oc[c][r] *= scale_[r];

        __syncthreads();   // P_lds write -> read visibility (lgkmcnt drain)

        // ---- P A-fragments: row i = l15, m = ks*32 + lg*8 ----
        bf16x8 pah0 = *(const bf16x8*)&Pl[w][0][l15][lg * 8];
        bf16x8 pah1 = *(const bf16x8*)&Pl[w][0][l15][32 + lg * 8];
        bf16x8 pal0 = *(const bf16x8*)&Pl[w][1][l15][lg * 8];
        bf16x8 pal1 = *(const bf16x8*)&Pl[w][1][l15][32 + lg * 8];

        // ---------------- O += P V ----------------
        const __bf16* vh_p = Vth + base + (size_t)l15 * N_ + mt + lg * 8;
        const __bf16* vl_p = Vtl + base + (size_t)l15 * N_ + mt + lg * 8;
        #pragma unroll
        for (int cs = 0; cs < 16; ++cs) {
            const __bf16* vh_c = vh_p + (size_t)cs * 16 * N_;
            const __bf16* vl_c = vl_p + (size_t)cs * 16 * N_;
            bf16x8 vh0 = *(const bf16x8*)(vh_c);
            bf16x8 vh1 = *(const bf16x8*)(vh_c + 32);
            bf16x8 vl0 = *(const bf16x8*)(vl_c);
            bf16x8 vl1 = *(const bf16x8*)(vl_c + 32);
            f32x4 a = oc[cs];
            a = __builtin_amdgcn_mfma_f32_16x16x32_bf16(pah0, vh0, a, 0, 0, 0);
            a = __builtin_amdgcn_mfma_f32_16x16x32_bf16(pah0, vl0, a, 0, 0, 0);
            a = __builtin_amdgcn_mfma_f32_16x16x32_bf16(pal0, vh0, a, 0, 0, 0);
            a = __builtin_amdgcn_mfma_f32_16x16x32_bf16(pah1, vh1, a, 0, 0, 0);
            a = __builtin_amdgcn_mfma_f32_16x16x32_bf16(pah1, vl1, a, 0, 0, 0);
            a = __builtin_amdgcn_mfma_f32_16x16x32_bf16(pal1, vh1, a, 0, 0, 0);
            oc[cs] = a;
        }
    }

    // ---------------- epilogue ----------------
    float inv[4];
    #pragma unroll
    for (int r = 0; r < 4; ++r) inv[r] = 1.0f / l_run[r];
    #pragma unroll
    for (int cs = 0; cs < 16; ++cs)
        #pragma unroll
        for (int r = 0; r < 4; ++r)
            O[base + (size_t)(n0 + w * 16 + lg * 4 + r) * C_ + cs * 16 + l15] =
                oc[cs][r] * inv[r];
}

// ---------------------------------------------------------------------------
extern "C" void kernel_launch(void* const* d_in, const int* in_sizes, int n_in,
                              void* d_out, int out_size, void* d_ws, size_t ws_size,
                              hipStream_t stream)
{
    const float* tgt = (const float*)d_in[0];
    const float* src = (const float*)d_in[1];
    const float* qw  = (const float*)d_in[2];
    const float* qb  = (const float*)d_in[3];
    const float* kw  = (const float*)d_in[4];
    const float* kb  = (const float*)d_in[5];
    const float* vw  = (const float*)d_in[6];
    const float* vb  = (const float*)d_in[7];
    float* out = (float*)d_out;

    // ws layout (6 x 8.39MB = 48MB):
    // [0]=Q_hi (first: Vnc_hi) [1]=Q_lo (first: Vnc_lo) [2]=K_hi [3]=K_lo
    // [4]=Vt_hi [5]=Vt_lo
    const size_t SZ = (size_t)B_ * N_ * C_;           // elems per buffer
    __bf16* w0 = (__bf16*)d_ws;
    __bf16* w1 = w0 + SZ;
    __bf16* w2 = w1 + SZ;
    __bf16* w3 = w2 + SZ;
    __bf16* w4 = w3 + SZ;
    __bf16* w5 = w4 + SZ;

    dim3 pgrid(P_ / 64, C_ / 64, B_);

    // 1) V projection -> Vnc (in the future-Q region)
    proj_kernel<<<pgrid, 256, 0, stream>>>(src, vw, vb, w0, w1);
    // 2) transpose Vnc -> Vt
    dim3 tgrid(N_ / 64, C_ / 64, B_ * 2);
    transpose_kernel<<<tgrid, 256, 0, stream>>>(
        (const ushort*)w0, (const ushort*)w1, (ushort*)w4, (ushort*)w5);
    // 3) Q projection (overwrites dead Vnc region)
    proj_kernel<<<pgrid, 256, 0, stream>>>(tgt, qw, qb, w0, w1);
    // 4) K projection
    proj_kernel<<<pgrid, 256, 0, stream>>>(src, kw, kb, w2, w3);
    // 5) attention
    dim3 agrid(N_ / 64, B_);
    attn_kernel<<<agrid, 256, 0, stream>>>(w0, w1, w2, w3, w4, w5, out);
}